// Round 10
// baseline (169.424 us; speedup 1.0000x reference)
//
#include <hip/hip_runtime.h>

#define NW    16
#define NEUR  128
#define NPTS  65536
#define SIGMA 0.02f
#define U_MEAN 0.0f
#define U_SD   1.0f
#define DELTA 0.19f          // cull radius (measured: absmax unchanged vs no-cull)

#define TILE   128          // points per block
#define NTHR   512          // 8 waves
#define HPAD   136          // LDS h2 row stride: 272B, 16B-aligned (R2: 132 -> misaligned-b128 replay)
#define MAT_HALVES 16384                  // frag-linear fp16 matrix: 128x128, no pad
#define WT_HALVES (2*NW*MAT_HALVES)       // 524288 halves = 1,048,576 B
#define WT_BYTES (WT_HALVES*2)
#define CNT_OFF  WT_BYTES                 // 256 ints (cnt16[w*16+s])
#define IDX_OFF  (WT_BYTES + 1024)        // segmented u16 lists, 1 MB
#define NSEG   16
#define SEGPTS (NPTS/NSEG)                // 4096 points scanned per bucket block
#define CAPSEG 2048                       // max fill ~1910 (mean 1812 + 3sigma; edges ~1034)
#define CHUNKS 256

typedef _Float16 half8 __attribute__((ext_vector_type(8)));
typedef float    f32x4 __attribute__((ext_vector_type(4)));

__device__ __forceinline__ float tanh_fast(float x) {
    float e = __expf(2.0f * x);
    return 1.0f - 2.0f * __builtin_amdgcn_rcpf(1.0f + e);
}

// ONE aux dispatch. Roles by blockIdx.x:
//   [0,32)    prep: W_hid fp32 [lw][d][e] -> wt fp16 FRAG-LINEAR:
//             half offset = (s*8+c)*512 + lane*8 + j  holding W[e=c*16+m][d=s*32+q*8+j],
//             lane=q*16+m.  A wave's B-fragment (s,c) is a contiguous, coalesced 1 KB.
//   [32,288)  bucket: segment s of window w -> compacted u16 list + cnt16
//   [288,320) zero out[]
__global__ __launch_bounds__(512) void aux_kernel(
    const float* __restrict__ W_hid, const float* __restrict__ x,
    const float* __restrict__ mids,  _Float16* __restrict__ wt,
    int* __restrict__ cnt16, unsigned short* __restrict__ idx,
    float* __restrict__ out)
{
    const int b = blockIdx.x;
    const int t = threadIdx.x;

    if (b < 32) {                          // ---- prep: one 128x128 matrix per block
        __shared__ __align__(16) _Float16 tile[NEUR * HPAD];   // [e][HPAD] transpose staging
        const int lw = b;
        const float4* src = (const float4*)(W_hid + (size_t)lw * NEUR * NEUR);
#pragma unroll
        for (int it = 0; it < 8; ++it) {   // 4096 float4, coalesced over e
            int f4 = it * 512 + t;
            int d  = f4 >> 5;
            int e0 = (f4 & 31) << 2;
            float4 v = src[f4];
            tile[(e0 + 0) * HPAD + d] = (_Float16)v.x;
            tile[(e0 + 1) * HPAD + d] = (_Float16)v.y;
            tile[(e0 + 2) * HPAD + d] = (_Float16)v.z;
            tile[(e0 + 3) * HPAD + d] = (_Float16)v.w;
        }
        __syncthreads();
        half8* dst8 = (half8*)(wt + (size_t)lw * MAT_HALVES);  // 2048 half8 chunks
#pragma unroll
        for (int it = 0; it < 4; ++it) {
            int h8 = it * 512 + t;
            int sc = h8 >> 6;              // s*8+c
            int ln = h8 & 63;              // lane = q*16+m
            int s_ = sc >> 3, c_ = sc & 7;
            int q_ = ln >> 4, m_ = ln & 15;
            dst8[h8] = *(const half8*)&tile[(c_ * 16 + m_) * HPAD + s_ * 32 + q_ * 8];
        }
    } else if (b < 288) {                  // ---- bucket: (segment, window)
        const int s = (b - 32) & (NSEG - 1);
        const int w = (b - 32) >> 4;
        __shared__ int lcnt;
        if (t == 0) lcnt = 0;
        __syncthreads();
        const float lo = mids[w] - DELTA;
        const float hi = mids[w + 1] + DELTA;
        const int lane = t & 63;
        unsigned short* dst = idx + (size_t)(w * NSEG + s) * CAPSEG;
#pragma unroll
        for (int it = 0; it < SEGPTS / 512; ++it) {
            int i = s * SEGPTS + it * 512 + t;
            float xv = x[i];
            bool need = (xv >= lo) && (xv <= hi);
            unsigned long long mask = __ballot(need);
            if (mask) {
                int leader = (int)__builtin_ctzll(mask);
                int total  = (int)__popcll(mask);
                int rank   = (int)__popcll(mask & ((1ull << lane) - 1ull));
                int base = 0;
                if (lane == leader) base = atomicAdd(&lcnt, total);   // LDS atomic
                base = __shfl(base, leader);
                int slot = base + rank;
                if (need && slot < CAPSEG) dst[slot] = (unsigned short)i;
            }
        }
        __syncthreads();
        if (t == 0) cnt16[w * NSEG + s] = lcnt;
    } else {                               // ---- zero out[]
        int i4 = (b - 288) * 512 + t;
        float4 z = {0.f, 0.f, 0.f, 0.f};
        ((float4*)out)[i4] = z;
    }
}

__global__ __launch_bounds__(NTHR, 8) void fbpinn_main(
    const float* __restrict__ x,     const float* __restrict__ means,
    const float* __restrict__ stds,  const float* __restrict__ mids,
    const float* __restrict__ W_in,  const float* __restrict__ b_in,
    const float* __restrict__ b_hid, const float* __restrict__ W_out,
    const float* __restrict__ b_out, const _Float16* __restrict__ wt,
    const int* __restrict__ cnt16,   const unsigned short* __restrict__ idx,
    float* __restrict__ out)
{
    const int w    = blockIdx.y;
    const int base = blockIdx.x * TILE;

    __shared__ __align__(16) _Float16 Hlds[TILE * HPAD];   // h2 only: 34816 B
    __shared__ float xs[TILE];
    __shared__ float wouts[NEUR];
    __shared__ unsigned short gis[TILE];

    const int t    = threadIdx.x;
    const int lane = t & 63;
    const int wave = t >> 6;
    const int m    = lane & 15;
    const int q    = lane >> 4;
    const int row0 = wave * 16;
    const int rsel = m & 3;

    // uniform per-thread scan of cnt16 (scalar loads; no barrier)
    int csh[NSEG];
    int total = 0;
#pragma unroll
    for (int k = 0; k < NSEG; ++k) {
        int c = cnt16[w * NSEG + k];
        c = c > CAPSEG ? CAPSEG : c;
        csh[k] = c;
        total += c;
    }
    if (base >= total) return;                        // uniform exit
    const int nvalid = min(TILE, total - base);

    // gather via segment resolution against the true running prefix (R7 fix)
    if (t < TILE) {
        int v = base + min(t, nvalid - 1);
        int seg = 0, segbase = 0, pre = 0;
#pragma unroll
        for (int k = 0; k < NSEG - 1; ++k) {
            pre += csh[k];
            if (v >= pre) { seg = k + 1; segbase = pre; }
        }
        unsigned short gi = idx[(size_t)(w * NSEG + seg) * CAPSEG + (v - segbase)];
        gis[t] = gi;
        xs[t]  = x[gi];
    }
    if (t < NEUR) wouts[t] = W_out[w * NEUR + t];
    __syncthreads();   // the ONLY barrier: xs/gis/wouts visible

    // B-fragment base pointers (frag-linear wt): frag (s,c) at bw[(s*8+c)*64]
    const half8* b0 = (const half8*)(wt + (size_t)(0 * NW + w) * MAT_HALVES) + lane;
    const half8* b1 = (const half8*)(wt + (size_t)(1 * NW + w) * MAT_HALVES) + lane;

    // layer 0 straight into GEMM1 A-fragments (registers)
    const float xn = (xs[row0 + m] - means[w]) * __builtin_amdgcn_rcpf(stds[w]);
    const float* win = W_in + w * NEUR;
    const float* bin = b_in + w * NEUR;
    half8 af[4];
#pragma unroll
    for (int s = 0; s < 4; ++s) {
        const int n0 = s * 32 + q * 8;
        float4 wv0 = *(const float4*)&win[n0];
        float4 wv1 = *(const float4*)&win[n0 + 4];
        float4 bv0 = *(const float4*)&bin[n0];
        float4 bv1 = *(const float4*)&bin[n0 + 4];
        af[s][0] = (_Float16)tanh_fast(fmaf(xn, wv0.x, bv0.x));
        af[s][1] = (_Float16)tanh_fast(fmaf(xn, wv0.y, bv0.y));
        af[s][2] = (_Float16)tanh_fast(fmaf(xn, wv0.z, bv0.z));
        af[s][3] = (_Float16)tanh_fast(fmaf(xn, wv0.w, bv0.w));
        af[s][4] = (_Float16)tanh_fast(fmaf(xn, wv1.x, bv1.x));
        af[s][5] = (_Float16)tanh_fast(fmaf(xn, wv1.y, bv1.y));
        af[s][6] = (_Float16)tanh_fast(fmaf(xn, wv1.z, bv1.z));
        af[s][7] = (_Float16)tanh_fast(fmaf(xn, wv1.w, bv1.w));
    }

    // GEMM1: z2 = h1 @ W0^T-frag (A regs, B from global/L1 — identical across waves)
    f32x4 acc[8];
    const f32x4 zz = {0.f, 0.f, 0.f, 0.f};
#pragma unroll
    for (int c = 0; c < 8; ++c) acc[c] = zz;
#pragma unroll
    for (int s = 0; s < 4; ++s) {
#pragma unroll
        for (int c = 0; c < 8; ++c)
            acc[c] = __builtin_amdgcn_mfma_f32_16x16x32_f16(af[s], b0[(s * 8 + c) * 64], acc[c], 0, 0, 0);
    }

    // h2 = tanh(z2+b) -> Hlds. Wave writes rows [row0,row0+16) and GEMM2 reads
    // the same rows -> per-wave self-dependency, NO barrier needed.
    {
        const float* bh0 = b_hid + (0 * NW + w) * NEUR;
#pragma unroll
        for (int c = 0; c < 8; ++c) {
            float bb = bh0[c * 16 + m];
#pragma unroll
            for (int r = 0; r < 4; ++r)
                Hlds[(row0 + q * 4 + r) * HPAD + c * 16 + m] = (_Float16)tanh_fast(acc[c][r] + bb);
        }
    }

    // GEMM2: z3 = h2 @ W1^T-frag (A rows from own slab of Hlds, B from global/L1)
#pragma unroll
    for (int c = 0; c < 8; ++c) acc[c] = zz;
#pragma unroll
    for (int s = 0; s < 4; ++s) {
        half8 a = *(const half8*)(Hlds + (row0 + m) * HPAD + s * 32 + q * 8);
#pragma unroll
        for (int c = 0; c < 8; ++c)
            acc[c] = __builtin_amdgcn_mfma_f32_16x16x32_f16(a, b1[(s * 8 + c) * 64], acc[c], 0, 0, 0);
    }

    // register epilogue: h3 = tanh(z3+b); out = h3 . W_out ; reduce over 16 m-lanes
    const float* bh1 = b_hid + (1 * NW + w) * NEUR;
    float t0 = 0.f, t1 = 0.f, t2 = 0.f, t3 = 0.f;
#pragma unroll
    for (int c = 0; c < 8; ++c) {
        float b  = bh1[c * 16 + m];
        float wo = wouts[c * 16 + m];
        t0 = fmaf(tanh_fast(acc[c][0] + b), wo, t0);
        t1 = fmaf(tanh_fast(acc[c][1] + b), wo, t1);
        t2 = fmaf(tanh_fast(acc[c][2] + b), wo, t2);
        t3 = fmaf(tanh_fast(acc[c][3] + b), wo, t3);
    }
    t0 += __shfl_xor(t0, 1); t1 += __shfl_xor(t1, 1);
    t2 += __shfl_xor(t2, 1); t3 += __shfl_xor(t3, 1);
    t0 += __shfl_xor(t0, 2); t1 += __shfl_xor(t1, 2);
    t2 += __shfl_xor(t2, 2); t3 += __shfl_xor(t3, 2);
    float v = (rsel == 0) ? t0 : (rsel == 1) ? t1 : (rsel == 2) ? t2 : t3;
    v += __shfl_xor(v, 4);
    v += __shfl_xor(v, 8);

    const int slot = row0 + q * 4 + rsel;
    if (m < 4 && slot < nvalid) {
        float u   = (v + b_out[w]) * U_SD + U_MEAN;
        float xv  = xs[slot];
        float xl  = (xv - mids[w])     * (1.0f / SIGMA);
        float xr  = (xv - mids[w + 1]) * (1.0f / SIGMA);
        float wf  = __builtin_amdgcn_rcpf(1.0f + __expf(xl)) *
                    __builtin_amdgcn_rcpf(1.0f + __expf(-xr));
        atomicAdd(&out[gis[slot]], wf * u);
    }
}

extern "C" void kernel_launch(void* const* d_in, const int* in_sizes, int n_in,
                              void* d_out, int out_size, void* d_ws, size_t ws_size,
                              hipStream_t stream) {
    const float* x     = (const float*)d_in[0];
    const float* means = (const float*)d_in[1];
    const float* stds  = (const float*)d_in[2];
    const float* mids  = (const float*)d_in[3];
    const float* W_in  = (const float*)d_in[4];
    const float* b_in  = (const float*)d_in[5];
    const float* W_hid = (const float*)d_in[6];
    const float* b_hid = (const float*)d_in[7];
    const float* W_out = (const float*)d_in[8];
    const float* b_out = (const float*)d_in[9];
    float* out = (float*)d_out;

    _Float16*       wt    = (_Float16*)d_ws;                          // 1,048,576 B
    int*            cnt16 = (int*)((char*)d_ws + CNT_OFF);            // 1 KB
    unsigned short* idx   = (unsigned short*)((char*)d_ws + IDX_OFF); // 1 MB  (total ~2.05 MB)

    aux_kernel<<<320, 512, 0, stream>>>(W_hid, x, mids, wt, cnt16, idx, out);
    fbpinn_main<<<dim3(CHUNKS, NW), NTHR, 0, stream>>>(
        x, means, stds, mids, W_in, b_in, b_hid, W_out, b_out, wt, cnt16, idx, out);
}

// Round 11
// 162.600 us; speedup vs baseline: 1.0420x; 1.0420x over previous
//
#include <hip/hip_runtime.h>

#define NW    16
#define NEUR  128
#define NPTS  65536
#define SIGMA 0.02f
#define U_MEAN 0.0f
#define U_SD   1.0f
#define DELTA 0.19f          // cull radius (measured: absmax unchanged vs no-cull)

#define TILE   128          // points per block
#define NTHR   256          // 4 waves x 32 rows each
#define HPAD   136          // 272B rows: 16B-aligned (R2: 132 -> misaligned-b128 replay)
#define WMAT_HALVES (NEUR*HPAD)           // 17408 halves = 34816 B per matrix
#define WT_TOTAL (2*NW*WMAT_HALVES)       // 557056 halves = 1,114,112 B
#define WT_BYTES (WT_TOTAL*2)
#define CNT_OFF  WT_BYTES                 // 256 ints (cnt16[w*16+s])
#define IDX_OFF  (WT_BYTES + 1024)        // segmented u16 lists, 1 MB
#define NSEG   16
#define SEGPTS (NPTS/NSEG)
#define CAPSEG 2048                       // max fill ~1910
#define CHUNKS 256

typedef _Float16 half8 __attribute__((ext_vector_type(8)));
typedef float    f32x4 __attribute__((ext_vector_type(4)));

__device__ __forceinline__ float tanh_fast(float x) {
    float e = __expf(2.0f * x);
    return 1.0f - 2.0f * __builtin_amdgcn_rcpf(1.0f + e);
}

// ONE aux dispatch (R9 version: wt in [lw][e][HPAD] layout). Roles by blockIdx.x:
//   [0,32) prep | [32,288) bucket | [288,320) zero out[]
__global__ __launch_bounds__(512) void aux_kernel(
    const float* __restrict__ W_hid, const float* __restrict__ x,
    const float* __restrict__ mids,  _Float16* __restrict__ wt,
    int* __restrict__ cnt16, unsigned short* __restrict__ idx,
    float* __restrict__ out)
{
    const int b = blockIdx.x;
    const int t = threadIdx.x;

    if (b < 32) {                          // ---- prep: one 128x128 matrix per block
        __shared__ __align__(16) _Float16 tile[NEUR * HPAD];   // 34816 B
        const int lw = b;
        const float4* src = (const float4*)(W_hid + (size_t)lw * NEUR * NEUR);
#pragma unroll
        for (int it = 0; it < 8; ++it) {   // 4096 float4, coalesced over e
            int f4 = it * 512 + t;
            int d  = f4 >> 5;
            int e0 = (f4 & 31) << 2;
            float4 v = src[f4];
            tile[(e0 + 0) * HPAD + d] = (_Float16)v.x;
            tile[(e0 + 1) * HPAD + d] = (_Float16)v.y;
            tile[(e0 + 2) * HPAD + d] = (_Float16)v.z;
            tile[(e0 + 3) * HPAD + d] = (_Float16)v.w;
        }
        if (t < NEUR) {                    // zero k-pad halves d in [128,136)
            half8 z; for (int j = 0; j < 8; ++j) z[j] = (_Float16)0.0f;
            *(half8*)&tile[t * HPAD + NEUR] = z;
        }
        __syncthreads();
        _Float16* dst = wt + (size_t)lw * WMAT_HALVES;
#pragma unroll
        for (int it = 0; it < 5; ++it) {   // 2176 half8 chunks, linear b128 copy
            int chunk = it * 512 + t;
            if (chunk < WMAT_HALVES / 8)
                *(half8*)&dst[chunk * 8] = *(const half8*)&tile[chunk * 8];
        }
    } else if (b < 288) {                  // ---- bucket: (segment, window)
        const int s = (b - 32) & (NSEG - 1);
        const int w = (b - 32) >> 4;
        __shared__ int lcnt;
        if (t == 0) lcnt = 0;
        __syncthreads();
        const float lo = mids[w] - DELTA;
        const float hi = mids[w + 1] + DELTA;
        const int lane = t & 63;
        unsigned short* dst = idx + (size_t)(w * NSEG + s) * CAPSEG;
#pragma unroll
        for (int it = 0; it < SEGPTS / 512; ++it) {
            int i = s * SEGPTS + it * 512 + t;
            float xv = x[i];
            bool need = (xv >= lo) && (xv <= hi);
            unsigned long long mask = __ballot(need);
            if (mask) {
                int leader = (int)__builtin_ctzll(mask);
                int total  = (int)__popcll(mask);
                int rank   = (int)__popcll(mask & ((1ull << lane) - 1ull));
                int base = 0;
                if (lane == leader) base = atomicAdd(&lcnt, total);   // LDS atomic
                base = __shfl(base, leader);
                int slot = base + rank;
                if (need && slot < CAPSEG) dst[slot] = (unsigned short)i;
            }
        }
        __syncthreads();
        if (t == 0) cnt16[w * NSEG + s] = lcnt;
    } else {                               // ---- zero out[]
        int i4 = (b - 288) * 512 + t;
        float4 z = {0.f, 0.f, 0.f, 0.f};
        ((float4*)out)[i4] = z;
    }
}

__device__ __forceinline__ void stage_w(const float4* __restrict__ g, float4* l4, int t) {
    // 2176 float4 per matrix, 256 threads: 8 each + 128-thread tail
#pragma unroll
    for (int i = 0; i < 8; ++i) l4[i * 256 + t] = g[i * 256 + t];
    if (t < 128) l4[2048 + t] = g[2048 + t];
}

__global__ __launch_bounds__(NTHR, 2) void fbpinn_main(
    const float* __restrict__ x,     const float* __restrict__ means,
    const float* __restrict__ stds,  const float* __restrict__ mids,
    const float* __restrict__ W_in,  const float* __restrict__ b_in,
    const float* __restrict__ b_hid, const float* __restrict__ W_out,
    const float* __restrict__ b_out, const _Float16* __restrict__ wt,
    const int* __restrict__ cnt16,   const unsigned short* __restrict__ idx,
    float* __restrict__ out)
{
    const int w    = blockIdx.y;
    const int base = blockIdx.x * TILE;

    // WA: W0 during GEMM1, then h2. WB: W1.
    __shared__ __align__(16) _Float16 WA[WMAT_HALVES];   // 34816 B
    __shared__ __align__(16) _Float16 WB[WMAT_HALVES];   // 34816 B
    __shared__ float xs[TILE];
    __shared__ float wouts[NEUR];
    __shared__ unsigned short gis[TILE];

    const int t    = threadIdx.x;
    const int lane = t & 63;
    const int wave = t >> 6;           // 0..3
    const int m    = lane & 15;
    const int q    = lane >> 4;
    const int row0 = wave * 32;        // this wave's 32-row slab (2 A-frags)
    const int rsel = m & 3;

    // uniform per-thread scan of cnt16 (scalar loads; no barrier)
    int csh[NSEG];
    int total = 0;
#pragma unroll
    for (int k = 0; k < NSEG; ++k) {
        int c = cnt16[w * NSEG + k];
        c = c > CAPSEG ? CAPSEG : c;
        csh[k] = c;
        total += c;
    }
    if (base >= total) return;                        // uniform exit
    const int nvalid = min(TILE, total - base);

    // gather via segment resolution against the true running prefix (R7 fix)
    if (t < TILE) {
        int v = base + min(t, nvalid - 1);
        int seg = 0, segbase = 0, pre = 0;
#pragma unroll
        for (int k = 0; k < NSEG - 1; ++k) {
            pre += csh[k];
            if (v >= pre) { seg = k + 1; segbase = pre; }
        }
        unsigned short gi = idx[(size_t)(w * NSEG + seg) * CAPSEG + (v - segbase)];
        gis[t] = gi;
        xs[t]  = x[gi];
    }
    stage_w((const float4*)(wt + (size_t)(0 * NW + w) * WMAT_HALVES), (float4*)WA, t);
    stage_w((const float4*)(wt + (size_t)(1 * NW + w) * WMAT_HALVES), (float4*)WB, t);
    if (t < NEUR) wouts[t] = W_out[w * NEUR + t];
    __syncthreads();   // barrier 1: xs/gis/WA/WB/wouts visible

    // layer 0 straight into GEMM1 A-fragments for BOTH row slabs (registers)
    const float rstd = __builtin_amdgcn_rcpf(stds[w]);
    const float xn0 = (xs[row0 + m]      - means[w]) * rstd;
    const float xn1 = (xs[row0 + 16 + m] - means[w]) * rstd;
    const float* win = W_in + w * NEUR;
    const float* bin = b_in + w * NEUR;
    half8 af0[4], af1[4];
#pragma unroll
    for (int s = 0; s < 4; ++s) {
        const int n0 = s * 32 + q * 8;
        float4 wv0 = *(const float4*)&win[n0];
        float4 wv1 = *(const float4*)&win[n0 + 4];
        float4 bv0 = *(const float4*)&bin[n0];
        float4 bv1 = *(const float4*)&bin[n0 + 4];
#pragma unroll
        for (int j = 0; j < 4; ++j) {
            float wj = ((const float*)&wv0)[j], bj = ((const float*)&bv0)[j];
            af0[s][j] = (_Float16)tanh_fast(fmaf(xn0, wj, bj));
            af1[s][j] = (_Float16)tanh_fast(fmaf(xn1, wj, bj));
        }
#pragma unroll
        for (int j = 0; j < 4; ++j) {
            float wj = ((const float*)&wv1)[j], bj = ((const float*)&bv1)[j];
            af0[s][4 + j] = (_Float16)tanh_fast(fmaf(xn0, wj, bj));
            af1[s][4 + j] = (_Float16)tanh_fast(fmaf(xn1, wj, bj));
        }
    }

    // GEMM1: each B-fragment read once, used for BOTH row slabs (B ds_reads halved)
    f32x4 acc0[8], acc1[8];
    const f32x4 zz = {0.f, 0.f, 0.f, 0.f};
#pragma unroll
    for (int c = 0; c < 8; ++c) { acc0[c] = zz; acc1[c] = zz; }
#pragma unroll
    for (int s = 0; s < 4; ++s) {
#pragma unroll
        for (int c = 0; c < 8; ++c) {
            half8 b = *(const half8*)(WA + (c * 16 + m) * HPAD + s * 32 + q * 8);
            acc0[c] = __builtin_amdgcn_mfma_f32_16x16x32_f16(af0[s], b, acc0[c], 0, 0, 0);
            acc1[c] = __builtin_amdgcn_mfma_f32_16x16x32_f16(af1[s], b, acc1[c], 0, 0, 0);
        }
    }
    __syncthreads();   // barrier 2: all waves done reading WA (h2 overwrites it)

    // h2 -> WA rows [row0,row0+32). GEMM2 reads only these same rows -> no barrier after.
    {
        const float* bh0 = b_hid + (0 * NW + w) * NEUR;
#pragma unroll
        for (int c = 0; c < 8; ++c) {
            float bb = bh0[c * 16 + m];
#pragma unroll
            for (int r = 0; r < 4; ++r) {
                WA[(row0 + q * 4 + r) * HPAD + c * 16 + m]      = (_Float16)tanh_fast(acc0[c][r] + bb);
                WA[(row0 + 16 + q * 4 + r) * HPAD + c * 16 + m] = (_Float16)tanh_fast(acc1[c][r] + bb);
            }
        }
    }

    // GEMM2: A from own slab of WA, B from WB (each B-frag again feeds 2 MFMAs)
#pragma unroll
    for (int c = 0; c < 8; ++c) { acc0[c] = zz; acc1[c] = zz; }
#pragma unroll
    for (int s = 0; s < 4; ++s) {
        half8 a0 = *(const half8*)(WA + (row0 + m) * HPAD + s * 32 + q * 8);
        half8 a1 = *(const half8*)(WA + (row0 + 16 + m) * HPAD + s * 32 + q * 8);
#pragma unroll
        for (int c = 0; c < 8; ++c) {
            half8 b = *(const half8*)(WB + (c * 16 + m) * HPAD + s * 32 + q * 8);
            acc0[c] = __builtin_amdgcn_mfma_f32_16x16x32_f16(a0, b, acc0[c], 0, 0, 0);
            acc1[c] = __builtin_amdgcn_mfma_f32_16x16x32_f16(a1, b, acc1[c], 0, 0, 0);
        }
    }

    // epilogue per slab: h3 = tanh(z3+b); dot W_out; reduce over 16 m-lanes; window; atomicAdd
    const float* bh1 = b_hid + (1 * NW + w) * NEUR;
#pragma unroll
    for (int slab = 0; slab < 2; ++slab) {
        const f32x4* acc = slab ? acc1 : acc0;
        float t0 = 0.f, t1 = 0.f, t2 = 0.f, t3 = 0.f;
#pragma unroll
        for (int c = 0; c < 8; ++c) {
            float b  = bh1[c * 16 + m];
            float wo = wouts[c * 16 + m];
            t0 = fmaf(tanh_fast(acc[c][0] + b), wo, t0);
            t1 = fmaf(tanh_fast(acc[c][1] + b), wo, t1);
            t2 = fmaf(tanh_fast(acc[c][2] + b), wo, t2);
            t3 = fmaf(tanh_fast(acc[c][3] + b), wo, t3);
        }
        t0 += __shfl_xor(t0, 1); t1 += __shfl_xor(t1, 1);
        t2 += __shfl_xor(t2, 1); t3 += __shfl_xor(t3, 1);
        t0 += __shfl_xor(t0, 2); t1 += __shfl_xor(t1, 2);
        t2 += __shfl_xor(t2, 2); t3 += __shfl_xor(t3, 2);
        float v = (rsel == 0) ? t0 : (rsel == 1) ? t1 : (rsel == 2) ? t2 : t3;
        v += __shfl_xor(v, 4);
        v += __shfl_xor(v, 8);

        const int slot = row0 + slab * 16 + q * 4 + rsel;
        if (m < 4 && slot < nvalid) {
            float u   = (v + b_out[w]) * U_SD + U_MEAN;
            float xv  = xs[slot];
            float xl  = (xv - mids[w])     * (1.0f / SIGMA);
            float xr  = (xv - mids[w + 1]) * (1.0f / SIGMA);
            float wf  = __builtin_amdgcn_rcpf(1.0f + __expf(xl)) *
                        __builtin_amdgcn_rcpf(1.0f + __expf(-xr));
            atomicAdd(&out[gis[slot]], wf * u);
        }
    }
}

extern "C" void kernel_launch(void* const* d_in, const int* in_sizes, int n_in,
                              void* d_out, int out_size, void* d_ws, size_t ws_size,
                              hipStream_t stream) {
    const float* x     = (const float*)d_in[0];
    const float* means = (const float*)d_in[1];
    const float* stds  = (const float*)d_in[2];
    const float* mids  = (const float*)d_in[3];
    const float* W_in  = (const float*)d_in[4];
    const float* b_in  = (const float*)d_in[5];
    const float* W_hid = (const float*)d_in[6];
    const float* b_hid = (const float*)d_in[7];
    const float* W_out = (const float*)d_in[8];
    const float* b_out = (const float*)d_in[9];
    float* out = (float*)d_out;

    _Float16*       wt    = (_Float16*)d_ws;                          // 1,114,112 B
    int*            cnt16 = (int*)((char*)d_ws + CNT_OFF);            // 1 KB
    unsigned short* idx   = (unsigned short*)((char*)d_ws + IDX_OFF); // 1 MB

    aux_kernel<<<320, 512, 0, stream>>>(W_hid, x, mids, wt, cnt16, idx, out);
    fbpinn_main<<<dim3(CHUNKS, NW), NTHR, 0, stream>>>(
        x, means, stds, mids, W_in, b_in, b_hid, W_out, b_out, wt, cnt16, idx, out);
}